// Round 1
// baseline (290.581 us; speedup 1.0000x reference)
//
#include <hip/hip_runtime.h>
#include <hip/hip_bf16.h>

// Problem constants
#define B_   8
#define T_   8192
#define D_   128
#define K_   64
#define TC   32      // timesteps per chunk
#define NC   256     // chunks per batch  (TC*NC == T_)
#define SEG  16      // chunks per segment
#define NSEG 16      // segments (SEG*NSEG == NC)

typedef float  floatx4  __attribute__((ext_vector_type(4)));
typedef __bf16 bf16x8   __attribute__((ext_vector_type(8)));
typedef unsigned short ushortx8 __attribute__((ext_vector_type(8)));

__device__ inline unsigned short f2bf(float f) {
  unsigned u = __float_as_uint(f);
  u = u + 0x7FFFu + ((u >> 16) & 1u);   // RNE to bf16
  return (unsigned short)(u >> 16);
}
__device__ inline float bf2f(unsigned short h) {
  return __uint_as_float(((unsigned)h) << 16);
}

// ---------------------------------------------------------------------------
// K1: spectral norm of W (64x128).  G = W W^T via bf16 MFMA, 8 normalized
// squarings -> G^256, pick dominant column, fp32 Rayleigh via W.
// Writes ws[0] = 1/sigma.
// ---------------------------------------------------------------------------
#define MP 72  // LDS pitch (elements), multiple of 8 for 16B-aligned rows

__global__ __launch_bounds__(256) void k_sigma(const float* __restrict__ W,
                                               float* __restrict__ ws) {
  __shared__ unsigned short Ma[64 * MP];
  __shared__ unsigned short Mb[64 * MP];
  __shared__ float red[4];
  __shared__ float vsh[64];
  __shared__ int   jsh;

  const int tid  = threadIdx.x;
  const int lane = tid & 63;
  const int wv   = tid >> 6;      // wave 0..3 -> C-tile row block
  const int l15  = lane & 15;
  const int q    = lane >> 4;     // 0..3

  // ---- G = W W^T : tiles (tm=wv, tn=0..3), K=128 in 4 steps of 32
  floatx4 acc[4] = {};
  const int arow = 16 * wv + l15;
  for (int s = 0; s < 4; ++s) {
    const int kb = 32 * s + 8 * q;
    float4 a0 = *(const float4*)(W + arow * 128 + kb);
    float4 a1 = *(const float4*)(W + arow * 128 + kb + 4);
    ushortx8 ua;
    ua[0] = f2bf(a0.x); ua[1] = f2bf(a0.y); ua[2] = f2bf(a0.z); ua[3] = f2bf(a0.w);
    ua[4] = f2bf(a1.x); ua[5] = f2bf(a1.y); ua[6] = f2bf(a1.z); ua[7] = f2bf(a1.w);
    bf16x8 av = __builtin_bit_cast(bf16x8, ua);
    for (int tn = 0; tn < 4; ++tn) {
      const int brow = 16 * tn + l15;          // B[k][n] = W[n][k]
      float4 b0 = *(const float4*)(W + brow * 128 + kb);
      float4 b1 = *(const float4*)(W + brow * 128 + kb + 4);
      ushortx8 ub;
      ub[0] = f2bf(b0.x); ub[1] = f2bf(b0.y); ub[2] = f2bf(b0.z); ub[3] = f2bf(b0.w);
      ub[4] = f2bf(b1.x); ub[5] = f2bf(b1.y); ub[6] = f2bf(b1.z); ub[7] = f2bf(b1.w);
      bf16x8 bv = __builtin_bit_cast(bf16x8, ub);
      acc[tn] = __builtin_amdgcn_mfma_f32_16x16x32_bf16(av, bv, acc[tn], 0, 0, 0);
    }
  }
  // normalize and store seed (C layout: col=lane&15, row=q*4+reg)
  float mx = 0.f;
  for (int tn = 0; tn < 4; ++tn)
    for (int r = 0; r < 4; ++r) mx = fmaxf(mx, fabsf(acc[tn][r]));
  for (int off = 32; off; off >>= 1) mx = fmaxf(mx, __shfl_xor(mx, off));
  if (lane == 0) red[wv] = mx;
  __syncthreads();
  {
    float gm  = fmaxf(fmaxf(red[0], red[1]), fmaxf(red[2], red[3]));
    float inv = 1.f / gm;
    for (int tn = 0; tn < 4; ++tn)
      for (int r = 0; r < 4; ++r)
        Ma[(16 * wv + 4 * q + r) * MP + 16 * tn + l15] = f2bf(acc[tn][r] * inv);
  }
  __syncthreads();

  // ---- 8 squarings (power 2^8 = 256)
  unsigned short* src = Ma;
  unsigned short* dst = Mb;
  for (int it = 0; it < 8; ++it) {
    floatx4 f[4] = {};
    for (int s = 0; s < 2; ++s) {
      const int kb = 32 * s + 8 * q;
      uint4 ua4 = *(const uint4*)(src + (16 * wv + l15) * MP + kb);
      bf16x8 av = __builtin_bit_cast(bf16x8, ua4);
      for (int tn = 0; tn < 4; ++tn) {
        const int n = 16 * tn + l15;
        ushortx8 ub;
        #pragma unroll
        for (int j = 0; j < 8; ++j) ub[j] = src[(kb + j) * MP + n];
        bf16x8 bv = __builtin_bit_cast(bf16x8, ub);
        f[tn] = __builtin_amdgcn_mfma_f32_16x16x32_bf16(av, bv, f[tn], 0, 0, 0);
      }
    }
    float m2 = 0.f;
    for (int tn = 0; tn < 4; ++tn)
      for (int r = 0; r < 4; ++r) m2 = fmaxf(m2, fabsf(f[tn][r]));
    for (int off = 32; off; off >>= 1) m2 = fmaxf(m2, __shfl_xor(m2, off));
    if (lane == 0) red[wv] = m2;
    __syncthreads();
    {
      float gm2  = fmaxf(fmaxf(red[0], red[1]), fmaxf(red[2], red[3]));
      float inv2 = 1.f / gm2;
      for (int tn = 0; tn < 4; ++tn)
        for (int r = 0; r < 4; ++r)
          dst[(16 * wv + 4 * q + r) * MP + 16 * tn + l15] = f2bf(f[tn][r] * inv2);
    }
    __syncthreads();
    unsigned short* t2 = src; src = dst; dst = t2;
  }

  // dominant column of G^256
  if (tid == 0) {
    int jb = 0; float best = -1.f;
    for (int j = 0; j < 64; ++j) {
      float dv = bf2f(src[j * MP + j]);
      if (dv > best) { best = dv; jb = j; }
    }
    jsh = jb;
  }
  __syncthreads();
  if (tid < 64) vsh[tid] = bf2f(src[tid * MP + jsh]);
  __syncthreads();

  // fp32 Rayleigh: sigma^2 = ||W^T v||^2 / ||v||^2
  if (wv == 0) {
    float wa = 0.f, wb = 0.f;
    for (int i = 0; i < 64; ++i) {
      float vi = vsh[i];
      wa = fmaf(W[i * 128 + lane], vi, wa);
      wb = fmaf(W[i * 128 + 64 + lane], vi, wb);
    }
    float num = wa * wa + wb * wb;
    float den = vsh[lane] * vsh[lane];
    for (int off = 32; off; off >>= 1) {
      num += __shfl_xor(num, off);
      den += __shfl_xor(den, off);
    }
    if (lane == 0) ws[0] = 1.f / sqrtf(num / den);
  }
}

// ---------------------------------------------------------------------------
// K2: V[bt][k] = sum_d x[bt][d] * W[k][d]   (unscaled; /sigma applied later)
// lane = k holds W row in 128 VGPRs; x row loads are wave-uniform -> scalar.
// ---------------------------------------------------------------------------
__global__ __launch_bounds__(256) void k_gemm(const float* __restrict__ x,
                                              const float* __restrict__ W,
                                              float* __restrict__ V) {
  const int lane = threadIdx.x & 63;
  const int wv   = __builtin_amdgcn_readfirstlane(threadIdx.x >> 6);
  const int gw   = blockIdx.x * 4 + wv;       // 0..2047, 32 rows each
  float w[128];
  const float4* W4 = (const float4*)(W + lane * 128);
  #pragma unroll
  for (int i = 0; i < 32; ++i) {
    float4 t = W4[i];
    w[4 * i] = t.x; w[4 * i + 1] = t.y; w[4 * i + 2] = t.z; w[4 * i + 3] = t.w;
  }
  const int row0 = gw * 32;
  for (int r = 0; r < 32; ++r) {
    const int row = row0 + r;
    const float* xr = x + (size_t)row * 128;  // wave-uniform address
    float acc = 0.f;
    #pragma unroll
    for (int d = 0; d < 128; d += 4) {
      float4 xv = *(const float4*)(xr + d);
      acc = fmaf(xv.x, w[d], acc);
      acc = fmaf(xv.y, w[d + 1], acc);
      acc = fmaf(xv.z, w[d + 2], acc);
      acc = fmaf(xv.w, w[d + 3], acc);
    }
    V[(size_t)row * 64 + lane] = acc;
  }
}

// Shared per-step math for K3/K5 (|theta| < 1.6e-3 so 2-term poly is exact)
#define STEP_PREP()                                                     \
    float alpha = alpha0 * __expf(a_ + tmv);                            \
    float omega = omega0 * __expf(o_ + tmv);                            \
    float rho = __expf(-alpha * dtv);                                   \
    float th  = omega * dtv;                                            \
    float th2 = th * th;                                                \
    float st  = th * fmaf(th2, -0.16666667f, 1.f);                      \
    float ct  = fmaf(th2, -0.5f, 1.f);                                  \
    float ar  = rho * ct, ai = rho * st;

// ---------------------------------------------------------------------------
// K3: per-chunk transform (A, U): wave=(b,c), lane=k, 32 sequential steps.
// ---------------------------------------------------------------------------
__global__ __launch_bounds__(256) void k_phaseA(
    const float* __restrict__ am, const float* __restrict__ om,
    const float* __restrict__ tm, const float* __restrict__ dtp,
    const float* __restrict__ V,  const float* __restrict__ sr,
    const float* __restrict__ si, const float* __restrict__ traw,
    const float* __restrict__ bb, const float* __restrict__ sig,
    float* __restrict__ T4) {
  const int lane = threadIdx.x & 63;
  const int wgl  = __builtin_amdgcn_readfirstlane(blockIdx.x * 4 + (threadIdx.x >> 6));
  const int b = wgl >> 8;
  const int c = wgl & (NC - 1);
  const float tau    = log1pf(__expf(traw[0])) + 1e-3f;
  const float alpha0 = (log1pf(__expf(sr[lane])) + 1e-6f) * tau;
  const float omega0 = si[lane] * tau;
  const float bk     = bb[lane];
  const float invs   = sig[0];
  const int bt0 = b * T_ + c * TC;
  size_t base = (size_t)bt0 * 64 + lane;
  float Ar = 1.f, Ai = 0.f, Ur = 0.f, Ui = 0.f;
  #pragma unroll 4
  for (int t = 0; t < TC; ++t) {
    float a_  = am[base];
    float o_  = om[base];
    float v_  = V[base];
    float tmv = tm[bt0 + t];
    float dtv = dtp[bt0 + t];
    STEP_PREP();
    float u   = fmaf(v_, invs, bk);
    float nUr = fmaf(ar, Ur, fmaf(-ai, Ui, u));
    float nUi = fmaf(ar, Ui, ai * Ur);
    Ur = nUr; Ui = nUi;
    float nAr = fmaf(ar, Ar, -ai * Ai);
    float nAi = fmaf(ar, Ai, ai * Ar);
    Ar = nAr; Ai = nAi;
    base += 64;
  }
  *(float4*)(T4 + (size_t)(c * 512 + b * 64 + lane) * 4) = make_float4(Ar, Ai, Ur, Ui);
}

// ---------------------------------------------------------------------------
// K4a: compose 16 chunk transforms -> segment aggregate. 8192 tasks.
// ---------------------------------------------------------------------------
__global__ __launch_bounds__(256) void k_segagg(const float* __restrict__ T4,
                                                float* __restrict__ SA) {
  const int t = blockIdx.x * 256 + threadIdx.x;  // 0..8191
  const int g = t >> 9;
  const int s = t & 511;
  float Ar = 1.f, Ai = 0.f, Ur = 0.f, Ui = 0.f;
  for (int i = 0; i < SEG; ++i) {
    const int c = g * SEG + i;
    float4 tr = *(const float4*)(T4 + (size_t)(c * 512 + s) * 4);
    float nUr = tr.x * Ur - tr.y * Ui + tr.z;   // new = T_i o cur
    float nUi = tr.x * Ui + tr.y * Ur + tr.w;
    float nAr = tr.x * Ar - tr.y * Ai;
    float nAi = tr.x * Ai + tr.y * Ar;
    Ar = nAr; Ai = nAi; Ur = nUr; Ui = nUi;
  }
  *(float4*)(SA + (size_t)t * 4) = make_float4(Ar, Ai, Ur, Ui);
}

// ---------------------------------------------------------------------------
// K4bc: per-sequence segment scan + expand to per-chunk initial states Z0.
// One block per sequence s = b*64+k.
// ---------------------------------------------------------------------------
__global__ __launch_bounds__(64) void k_segscan(const float* __restrict__ SA,
                                                const float* __restrict__ T4,
                                                float* __restrict__ Z0) {
  __shared__ float sz[NSEG * 2];
  const int s   = blockIdx.x;      // 0..511
  const int tid = threadIdx.x;
  if (tid == 0) {
    float zr = 0.f, zi = 0.f;
    #pragma unroll
    for (int g = 0; g < NSEG; ++g) {
      sz[2 * g] = zr; sz[2 * g + 1] = zi;
      float4 a = *(const float4*)(SA + (size_t)(g * 512 + s) * 4);
      float nr = a.x * zr - a.y * zi + a.z;
      float ni = a.x * zi + a.y * zr + a.w;
      zr = nr; zi = ni;
    }
  }
  __syncthreads();
  if (tid < NSEG) {
    float zr = sz[2 * tid], zi = sz[2 * tid + 1];
    for (int i = 0; i < SEG; ++i) {
      const int c = tid * SEG + i;
      const size_t o = (size_t)(c * 512 + s);
      Z0[o * 2] = zr; Z0[o * 2 + 1] = zi;
      float4 a = *(const float4*)(T4 + o * 4);
      float nr = a.x * zr - a.y * zi + a.z;
      float ni = a.x * zi + a.y * zr + a.w;
      zr = nr; zi = ni;
    }
  }
}

// ---------------------------------------------------------------------------
// K5: re-run recurrence per chunk from Z0, write out [C | S].
// ---------------------------------------------------------------------------
__global__ __launch_bounds__(256) void k_phaseC(
    const float* __restrict__ am, const float* __restrict__ om,
    const float* __restrict__ tm, const float* __restrict__ dtp,
    const float* __restrict__ V,  const float* __restrict__ sr,
    const float* __restrict__ si, const float* __restrict__ traw,
    const float* __restrict__ bb, const float* __restrict__ sig,
    const float* __restrict__ Z0, float* __restrict__ out) {
  const int lane = threadIdx.x & 63;
  const int wgl  = __builtin_amdgcn_readfirstlane(blockIdx.x * 4 + (threadIdx.x >> 6));
  const int b = wgl >> 8;
  const int c = wgl & (NC - 1);
  const float tau    = log1pf(__expf(traw[0])) + 1e-3f;
  const float alpha0 = (log1pf(__expf(sr[lane])) + 1e-6f) * tau;
  const float omega0 = si[lane] * tau;
  const float bk     = bb[lane];
  const float invs   = sig[0];
  const size_t zo = (size_t)(c * 512 + b * 64 + lane) * 2;
  float zr = Z0[zo], zi = Z0[zo + 1];
  const int bt0 = b * T_ + c * TC;
  size_t base = (size_t)bt0 * 64 + lane;
  float* outp = out + (size_t)bt0 * 128 + lane;
  #pragma unroll 4
  for (int t = 0; t < TC; ++t) {
    float a_  = am[base];
    float o_  = om[base];
    float v_  = V[base];
    float tmv = tm[bt0 + t];
    float dtv = dtp[bt0 + t];
    STEP_PREP();
    float u  = fmaf(v_, invs, bk);
    float nr = fmaf(ar, zr, fmaf(-ai, zi, u));
    float ni = fmaf(ar, zi, ai * zr);
    zr = nr; zi = ni;
    outp[0]  = zr;     // C
    outp[64] = zi;     // S
    base += 64; outp += 128;
  }
}

// ---------------------------------------------------------------------------
extern "C" void kernel_launch(void* const* d_in, const int* in_sizes, int n_in,
                              void* d_out, int out_size, void* d_ws, size_t ws_size,
                              hipStream_t stream) {
  (void)in_sizes; (void)n_in; (void)out_size; (void)ws_size;
  const float* x    = (const float*)d_in[0];
  const float* dtp  = (const float*)d_in[1];
  const float* amod = (const float*)d_in[2];
  const float* omod = (const float*)d_in[3];
  const float* tmod = (const float*)d_in[4];
  const float* srr  = (const float*)d_in[5];
  const float* sim  = (const float*)d_in[6];
  const float* traw = (const float*)d_in[7];
  const float* W    = (const float*)d_in[8];
  const float* bb   = (const float*)d_in[9];
  float* out = (float*)d_out;
  float* ws  = (float*)d_ws;

  float* sig = ws;                                   // [16]
  float* V   = ws + 16;                              // 4194304
  float* T4  = V  + (size_t)B_ * T_ * K_;            // 524288
  float* SA  = T4 + (size_t)NC * 512 * 4;            // 32768
  float* Z0  = SA + (size_t)NSEG * 512 * 4;          // 262144

  k_sigma  <<<1,   256, 0, stream>>>(W, sig);
  k_gemm   <<<512, 256, 0, stream>>>(x, W, V);
  k_phaseA <<<512, 256, 0, stream>>>(amod, omod, tmod, dtp, V, srr, sim, traw, bb, sig, T4);
  k_segagg <<<32,  256, 0, stream>>>(T4, SA);
  k_segscan<<<512, 64,  0, stream>>>(SA, T4, Z0);
  k_phaseC <<<512, 256, 0, stream>>>(amod, omod, tmod, dtp, V, srr, sim, traw, bb, sig, Z0, out);
}

// Round 2
// 166.496 us; speedup vs baseline: 1.7453x; 1.7453x over previous
//
#include <hip/hip_runtime.h>
#include <hip/hip_bf16.h>

// Problem constants
#define B_   8
#define T_   8192
#define D_   128
#define K_   64
#define TC   16      // timesteps per chunk
#define NC   512     // chunks per batch  (TC*NC == T_)
#define SEG  16      // chunks per segment
#define NSEG 32      // segments (SEG*NSEG == NC)

#define GEMM_BLOCKS 1024
#define GP 136       // LDS pitch (ushorts) for W hi/lo rows: 2-way bank aliasing only

typedef float  floatx4  __attribute__((ext_vector_type(4)));
typedef __bf16 bf16x8   __attribute__((ext_vector_type(8)));
typedef unsigned short ushortx8 __attribute__((ext_vector_type(8)));

__device__ inline unsigned short f2bf(float f) {
  unsigned u = __float_as_uint(f);
  u = u + 0x7FFFu + ((u >> 16) & 1u);   // RNE to bf16
  return (unsigned short)(u >> 16);
}
__device__ inline float bf2f(unsigned short h) {
  return __uint_as_float(((unsigned)h) << 16);
}

// ---------------------------------------------------------------------------
// K1+K2 fused: blocks 0..1023 do the GEMM V = x * W^T (unscaled, fp32-accurate
// via bf16 hi/lo split + MFMA); block 1024 computes 1/sigma into sig[0].
// ---------------------------------------------------------------------------
#define MP 72  // sigma-path LDS pitch (ushorts)

__global__ __launch_bounds__(256) void k_gemm_sigma(
    const float* __restrict__ x, const float* __restrict__ W,
    float* __restrict__ V, float* __restrict__ sig) {
  __shared__ __align__(16) unsigned char smem[2 * 64 * GP * 2 + 512];

  const int tid  = threadIdx.x;
  const int lane = tid & 63;
  const int wv   = tid >> 6;
  const int l15  = lane & 15;
  const int q    = lane >> 4;

  if (blockIdx.x == GEMM_BLOCKS) {
    // ---------------- sigma path (one block) ----------------
    unsigned short* Ma = (unsigned short*)smem;            // 64*72
    unsigned short* Mb = Ma + 64 * MP;                     // 64*72
    float* red = (float*)(smem + 2 * 64 * MP * 2);
    float* vsh = red + 4;
    int*   jsh = (int*)(vsh + 64);

    // G = W W^T : tiles (tm=wv, tn=0..3), K=128 in 4 steps of 32
    floatx4 acc[4] = {};
    const int arow = 16 * wv + l15;
    for (int s = 0; s < 4; ++s) {
      const int kb = 32 * s + 8 * q;
      float4 a0 = *(const float4*)(W + arow * 128 + kb);
      float4 a1 = *(const float4*)(W + arow * 128 + kb + 4);
      ushortx8 ua;
      ua[0] = f2bf(a0.x); ua[1] = f2bf(a0.y); ua[2] = f2bf(a0.z); ua[3] = f2bf(a0.w);
      ua[4] = f2bf(a1.x); ua[5] = f2bf(a1.y); ua[6] = f2bf(a1.z); ua[7] = f2bf(a1.w);
      bf16x8 av = __builtin_bit_cast(bf16x8, ua);
      for (int tn = 0; tn < 4; ++tn) {
        const int brow = 16 * tn + l15;          // B[k][n] = W[n][k]
        float4 b0 = *(const float4*)(W + brow * 128 + kb);
        float4 b1 = *(const float4*)(W + brow * 128 + kb + 4);
        ushortx8 ub;
        ub[0] = f2bf(b0.x); ub[1] = f2bf(b0.y); ub[2] = f2bf(b0.z); ub[3] = f2bf(b0.w);
        ub[4] = f2bf(b1.x); ub[5] = f2bf(b1.y); ub[6] = f2bf(b1.z); ub[7] = f2bf(b1.w);
        bf16x8 bv = __builtin_bit_cast(bf16x8, ub);
        acc[tn] = __builtin_amdgcn_mfma_f32_16x16x32_bf16(av, bv, acc[tn], 0, 0, 0);
      }
    }
    float mx = 0.f;
    for (int tn = 0; tn < 4; ++tn)
      for (int r = 0; r < 4; ++r) mx = fmaxf(mx, fabsf(acc[tn][r]));
    for (int off = 32; off; off >>= 1) mx = fmaxf(mx, __shfl_xor(mx, off));
    if (lane == 0) red[wv] = mx;
    __syncthreads();
    {
      float gm  = fmaxf(fmaxf(red[0], red[1]), fmaxf(red[2], red[3]));
      float inv = 1.f / gm;
      for (int tn = 0; tn < 4; ++tn)
        for (int r = 0; r < 4; ++r)
          Ma[(16 * wv + 4 * q + r) * MP + 16 * tn + l15] = f2bf(acc[tn][r] * inv);
    }
    __syncthreads();

    unsigned short* src = Ma;
    unsigned short* dst = Mb;
    for (int it = 0; it < 8; ++it) {
      floatx4 f[4] = {};
      for (int s = 0; s < 2; ++s) {
        const int kb = 32 * s + 8 * q;
        uint4 ua4 = *(const uint4*)(src + (16 * wv + l15) * MP + kb);
        bf16x8 av = __builtin_bit_cast(bf16x8, ua4);
        for (int tn = 0; tn < 4; ++tn) {
          const int n = 16 * tn + l15;
          ushortx8 ub;
          #pragma unroll
          for (int j = 0; j < 8; ++j) ub[j] = src[(kb + j) * MP + n];
          bf16x8 bv = __builtin_bit_cast(bf16x8, ub);
          f[tn] = __builtin_amdgcn_mfma_f32_16x16x32_bf16(av, bv, f[tn], 0, 0, 0);
        }
      }
      float m2 = 0.f;
      for (int tn = 0; tn < 4; ++tn)
        for (int r = 0; r < 4; ++r) m2 = fmaxf(m2, fabsf(f[tn][r]));
      for (int off = 32; off; off >>= 1) m2 = fmaxf(m2, __shfl_xor(m2, off));
      if (lane == 0) red[wv] = m2;
      __syncthreads();
      {
        float gm2  = fmaxf(fmaxf(red[0], red[1]), fmaxf(red[2], red[3]));
        float inv2 = 1.f / gm2;
        for (int tn = 0; tn < 4; ++tn)
          for (int r = 0; r < 4; ++r)
            dst[(16 * wv + 4 * q + r) * MP + 16 * tn + l15] = f2bf(f[tn][r] * inv2);
      }
      __syncthreads();
      unsigned short* t2 = src; src = dst; dst = t2;
    }

    if (tid == 0) {
      int jb = 0; float best = -1.f;
      for (int j = 0; j < 64; ++j) {
        float dv = bf2f(src[j * MP + j]);
        if (dv > best) { best = dv; jb = j; }
      }
      *jsh = jb;
    }
    __syncthreads();
    if (tid < 64) vsh[tid] = bf2f(src[tid * MP + *jsh]);
    __syncthreads();

    if (wv == 0) {
      float wa = 0.f, wb = 0.f;
      for (int i = 0; i < 64; ++i) {
        float vi = vsh[i];
        wa = fmaf(W[i * 128 + lane], vi, wa);
        wb = fmaf(W[i * 128 + 64 + lane], vi, wb);
      }
      float num = wa * wa + wb * wb;
      float den = vsh[lane] * vsh[lane];
      for (int off = 32; off; off >>= 1) {
        num += __shfl_xor(num, off);
        den += __shfl_xor(den, off);
      }
      if (lane == 0) sig[0] = 1.f / sqrtf(num / den);
    }
    return;
  }

  // ---------------- GEMM path ----------------
  unsigned short* Wh = (unsigned short*)smem;   // [64][GP]
  unsigned short* Wl = Wh + 64 * GP;

  // stage W -> bf16 hi/lo in LDS (coalesced float4 loads)
  #pragma unroll
  for (int j = 0; j < 8; ++j) {
    const int v = tid + 256 * j;           // float4 index, 0..2047
    float4 w4 = ((const float4*)W)[v];
    const int e = v * 4;
    const int row = e >> 7, col = e & 127;
    float a[4] = {w4.x, w4.y, w4.z, w4.w};
    unsigned short h[4], l[4];
    #pragma unroll
    for (int i = 0; i < 4; ++i) {
      h[i] = f2bf(a[i]);
      l[i] = f2bf(a[i] - bf2f(h[i]));
    }
    unsigned hp0 = (unsigned)h[0] | ((unsigned)h[1] << 16);
    unsigned hp1 = (unsigned)h[2] | ((unsigned)h[3] << 16);
    unsigned lp0 = (unsigned)l[0] | ((unsigned)l[1] << 16);
    unsigned lp1 = (unsigned)l[2] | ((unsigned)l[3] << 16);
    *(uint2*)(Wh + row * GP + col) = make_uint2(hp0, hp1);
    *(uint2*)(Wl + row * GP + col) = make_uint2(lp0, lp1);
  }
  __syncthreads();

  const int R0 = blockIdx.x * 64 + wv * 16;   // 16 rows per wave
  floatx4 acc[4] = {};

  #pragma unroll
  for (int s = 0; s < 4; ++s) {
    // A fragment: rows R0 + l15, d = 32s + 8q .. +8, converted to hi/lo bf16
    const float* xp = x + ((size_t)(R0 + l15) << 7) + 32 * s + 8 * q;
    float4 x0 = *(const float4*)xp;
    float4 x1 = *(const float4*)(xp + 4);
    float xs8[8] = {x0.x, x0.y, x0.z, x0.w, x1.x, x1.y, x1.z, x1.w};
    ushortx8 uh, ul;
    #pragma unroll
    for (int j = 0; j < 8; ++j) {
      unsigned short h = f2bf(xs8[j]);
      uh[j] = h;
      ul[j] = f2bf(xs8[j] - bf2f(h));
    }
    bf16x8 ah = __builtin_bit_cast(bf16x8, uh);
    bf16x8 al = __builtin_bit_cast(bf16x8, ul);

    #pragma unroll
    for (int t = 0; t < 4; ++t) {
      const unsigned short* bp = Wh + (16 * t + l15) * GP + 32 * s + 8 * q;
      bf16x8 bh = __builtin_bit_cast(bf16x8, *(const uint4*)bp);
      const unsigned short* bq = Wl + (16 * t + l15) * GP + 32 * s + 8 * q;
      bf16x8 bl = __builtin_bit_cast(bf16x8, *(const uint4*)bq);
      acc[t] = __builtin_amdgcn_mfma_f32_16x16x32_bf16(ah, bh, acc[t], 0, 0, 0);
      acc[t] = __builtin_amdgcn_mfma_f32_16x16x32_bf16(al, bh, acc[t], 0, 0, 0);
      acc[t] = __builtin_amdgcn_mfma_f32_16x16x32_bf16(ah, bl, acc[t], 0, 0, 0);
    }
  }

  // store: C layout col = l15, row = 4q + r
  #pragma unroll
  for (int t = 0; t < 4; ++t)
    #pragma unroll
    for (int r = 0; r < 4; ++r)
      V[(size_t)(R0 + 4 * q + r) * 64 + 16 * t + l15] = acc[t][r];
}

// Shared per-step math for K3/K5 (|theta| < 1.6e-3 so 2-term poly is exact)
#define STEP_PREP()                                                     \
    float alpha = alpha0 * __expf(a_ + tmv);                            \
    float omega = omega0 * __expf(o_ + tmv);                            \
    float rho = __expf(-alpha * dtv);                                   \
    float th  = omega * dtv;                                            \
    float th2 = th * th;                                                \
    float st  = th * fmaf(th2, -0.16666667f, 1.f);                      \
    float ct  = fmaf(th2, -0.5f, 1.f);                                  \
    float ar  = rho * ct, ai = rho * st;

// ---------------------------------------------------------------------------
// K3: per-chunk transform (A, U): wave=(b,c), lane=k, TC sequential steps.
// ---------------------------------------------------------------------------
__global__ __launch_bounds__(256) void k_phaseA(
    const float* __restrict__ am, const float* __restrict__ om,
    const float* __restrict__ tm, const float* __restrict__ dtp,
    const float* __restrict__ V,  const float* __restrict__ sr,
    const float* __restrict__ si, const float* __restrict__ traw,
    const float* __restrict__ bb, const float* __restrict__ sig,
    float* __restrict__ T4) {
  const int lane = threadIdx.x & 63;
  const int wgl  = __builtin_amdgcn_readfirstlane(blockIdx.x * 4 + (threadIdx.x >> 6));
  const int b = wgl >> 9;
  const int c = wgl & (NC - 1);
  const float tau    = log1pf(__expf(traw[0])) + 1e-3f;
  const float alpha0 = (log1pf(__expf(sr[lane])) + 1e-6f) * tau;
  const float omega0 = si[lane] * tau;
  const float bk     = bb[lane];
  const float invs   = sig[0];
  const int bt0 = b * T_ + c * TC;
  size_t base = (size_t)bt0 * 64 + lane;
  float Ar = 1.f, Ai = 0.f, Ur = 0.f, Ui = 0.f;
  #pragma unroll 4
  for (int t = 0; t < TC; ++t) {
    float a_  = am[base];
    float o_  = om[base];
    float v_  = V[base];
    float tmv = tm[bt0 + t];
    float dtv = dtp[bt0 + t];
    STEP_PREP();
    float u   = fmaf(v_, invs, bk);
    float nUr = fmaf(ar, Ur, fmaf(-ai, Ui, u));
    float nUi = fmaf(ar, Ui, ai * Ur);
    Ur = nUr; Ui = nUi;
    float nAr = fmaf(ar, Ar, -ai * Ai);
    float nAi = fmaf(ar, Ai, ai * Ar);
    Ar = nAr; Ai = nAi;
    base += 64;
  }
  *(float4*)(T4 + (size_t)(c * 512 + b * 64 + lane) * 4) = make_float4(Ar, Ai, Ur, Ui);
}

// ---------------------------------------------------------------------------
// K4a: compose SEG chunk transforms -> segment aggregate. NSEG*512 tasks.
// ---------------------------------------------------------------------------
__global__ __launch_bounds__(256) void k_segagg(const float* __restrict__ T4,
                                                float* __restrict__ SA) {
  const int t = blockIdx.x * 256 + threadIdx.x;  // 0..NSEG*512-1
  const int g = t >> 9;
  const int s = t & 511;
  float Ar = 1.f, Ai = 0.f, Ur = 0.f, Ui = 0.f;
  for (int i = 0; i < SEG; ++i) {
    const int c = g * SEG + i;
    float4 tr = *(const float4*)(T4 + (size_t)(c * 512 + s) * 4);
    float nUr = tr.x * Ur - tr.y * Ui + tr.z;   // new = T_i o cur
    float nUi = tr.x * Ui + tr.y * Ur + tr.w;
    float nAr = tr.x * Ar - tr.y * Ai;
    float nAi = tr.x * Ai + tr.y * Ar;
    Ar = nAr; Ai = nAi; Ur = nUr; Ui = nUi;
  }
  *(float4*)(SA + (size_t)t * 4) = make_float4(Ar, Ai, Ur, Ui);
}

// ---------------------------------------------------------------------------
// K4bc: per-sequence segment scan + expand to per-chunk initial states Z0.
// One block per sequence s = b*64+k.
// ---------------------------------------------------------------------------
__global__ __launch_bounds__(64) void k_segscan(const float* __restrict__ SA,
                                                const float* __restrict__ T4,
                                                float* __restrict__ Z0) {
  __shared__ float sz[NSEG * 2];
  const int s   = blockIdx.x;      // 0..511
  const int tid = threadIdx.x;
  if (tid == 0) {
    float zr = 0.f, zi = 0.f;
    #pragma unroll
    for (int g = 0; g < NSEG; ++g) {
      sz[2 * g] = zr; sz[2 * g + 1] = zi;
      float4 a = *(const float4*)(SA + (size_t)(g * 512 + s) * 4);
      float nr = a.x * zr - a.y * zi + a.z;
      float ni = a.x * zi + a.y * zr + a.w;
      zr = nr; zi = ni;
    }
  }
  __syncthreads();
  if (tid < NSEG) {
    float zr = sz[2 * tid], zi = sz[2 * tid + 1];
    for (int i = 0; i < SEG; ++i) {
      const int c = tid * SEG + i;
      const size_t o = (size_t)(c * 512 + s);
      Z0[o * 2] = zr; Z0[o * 2 + 1] = zi;
      float4 a = *(const float4*)(T4 + o * 4);
      float nr = a.x * zr - a.y * zi + a.z;
      float ni = a.x * zi + a.y * zr + a.w;
      zr = nr; zi = ni;
    }
  }
}

// ---------------------------------------------------------------------------
// K5: re-run recurrence per chunk from Z0, write out [C | S].
// ---------------------------------------------------------------------------
__global__ __launch_bounds__(256) void k_phaseC(
    const float* __restrict__ am, const float* __restrict__ om,
    const float* __restrict__ tm, const float* __restrict__ dtp,
    const float* __restrict__ V,  const float* __restrict__ sr,
    const float* __restrict__ si, const float* __restrict__ traw,
    const float* __restrict__ bb, const float* __restrict__ sig,
    const float* __restrict__ Z0, float* __restrict__ out) {
  const int lane = threadIdx.x & 63;
  const int wgl  = __builtin_amdgcn_readfirstlane(blockIdx.x * 4 + (threadIdx.x >> 6));
  const int b = wgl >> 9;
  const int c = wgl & (NC - 1);
  const float tau    = log1pf(__expf(traw[0])) + 1e-3f;
  const float alpha0 = (log1pf(__expf(sr[lane])) + 1e-6f) * tau;
  const float omega0 = si[lane] * tau;
  const float bk     = bb[lane];
  const float invs   = sig[0];
  const size_t zo = (size_t)(c * 512 + b * 64 + lane) * 2;
  float zr = Z0[zo], zi = Z0[zo + 1];
  const int bt0 = b * T_ + c * TC;
  size_t base = (size_t)bt0 * 64 + lane;
  float* outp = out + (size_t)bt0 * 128 + lane;
  #pragma unroll 4
  for (int t = 0; t < TC; ++t) {
    float a_  = am[base];
    float o_  = om[base];
    float v_  = V[base];
    float tmv = tm[bt0 + t];
    float dtv = dtp[bt0 + t];
    STEP_PREP();
    float u  = fmaf(v_, invs, bk);
    float nr = fmaf(ar, zr, fmaf(-ai, zi, u));
    float ni = fmaf(ar, zi, ai * zr);
    zr = nr; zi = ni;
    outp[0]  = zr;     // C
    outp[64] = zi;     // S
    base += 64; outp += 128;
  }
}

// ---------------------------------------------------------------------------
extern "C" void kernel_launch(void* const* d_in, const int* in_sizes, int n_in,
                              void* d_out, int out_size, void* d_ws, size_t ws_size,
                              hipStream_t stream) {
  (void)in_sizes; (void)n_in; (void)out_size; (void)ws_size;
  const float* x    = (const float*)d_in[0];
  const float* dtp  = (const float*)d_in[1];
  const float* amod = (const float*)d_in[2];
  const float* omod = (const float*)d_in[3];
  const float* tmod = (const float*)d_in[4];
  const float* srr  = (const float*)d_in[5];
  const float* sim  = (const float*)d_in[6];
  const float* traw = (const float*)d_in[7];
  const float* W    = (const float*)d_in[8];
  const float* bb   = (const float*)d_in[9];
  float* out = (float*)d_out;
  float* ws  = (float*)d_ws;

  float* sig = ws;                                   // [16]
  float* V   = ws + 16;                              // 4,194,304
  float* T4  = V  + (size_t)B_ * T_ * K_;            // NC*512*4 = 1,048,576
  float* SA  = T4 + (size_t)NC * 512 * 4;            // NSEG*512*4 = 65,536
  float* Z0  = SA + (size_t)NSEG * 512 * 4;          // NC*512*2 = 524,288

  k_gemm_sigma<<<GEMM_BLOCKS + 1, 256, 0, stream>>>(x, W, V, sig);
  k_phaseA <<<1024, 256, 0, stream>>>(amod, omod, tmod, dtp, V, srr, sim, traw, bb, sig, T4);
  k_segagg <<<NSEG * 2, 256, 0, stream>>>(T4, SA);
  k_segscan<<<512, 64,  0, stream>>>(SA, T4, Z0);
  k_phaseC <<<1024, 256, 0, stream>>>(amod, omod, tmod, dtp, V, srr, sim, traw, bb, sig, Z0, out);
}